// Round 4
// baseline (213.665 us; speedup 1.0000x reference)
//
#include <hip/hip_runtime.h>
#include <hip/hip_fp16.h>

// Fused Sinkhorn OT. n=64, in_size=1024, in_dim=128, heads=4, out_size=64.
// Single kernel, 256 blocks x 1024 threads (1 block/CU):
//   P1: K-GEMM (fp32 pk-fma, W^T staged LDS) -> EK=exp(K) in regs (8x8/thread)
//   P2: multiplicative Sinkhorn (DPP/swizzle reductions, 2 barriers/iter,
//       early exit tol 1e-4, cap 100)
//   P3: out = T^T x fused in-block: T written f16 to LDS in 4 chunks of 256
//       rows (XOR-swizzled layout), consumed by 4o x 8d per-thread fp32 tiles,
//       x from global (L2-warm; 16 lanes/wave share addresses).
// No T round-trip to HBM, no second dispatch.

__device__ __forceinline__ float2 pkfma(float2 a, float2 b, float2 c) {
  return make_float2(fmaf(a.x, b.x, c.x), fmaf(a.y, b.y, c.y));
}

template <int CTRL>
__device__ __forceinline__ float dpp_add(float v) {
  return v + __int_as_float(__builtin_amdgcn_update_dpp(
                 0, __float_as_int(v), CTRL, 0xf, 0xf, true));
}
__device__ __forceinline__ float swz16_add(float v) {
  return v + __int_as_float(
                 __builtin_amdgcn_ds_swizzle(__float_as_int(v), 0x401F));
}

// XCD-aware batch map: 4 heads of one nb + 8 nb per XCD (4 MB x-slice = L2).
__device__ __forceinline__ void batch_map(int bb, int& nb, int& m) {
  int k = bb >> 3;
  nb = 8 * (bb & 7) + (k >> 2);
  m = k & 3;
}

__global__ __launch_bounds__(1024, 4) void ot_fused_kernel(
    const float* __restrict__ x, const float* __restrict__ w,
    float* __restrict__ out) {
  int nb, m;
  batch_map(blockIdx.x, nb, m);
  const int t = threadIdx.x;
  const int gi = t >> 3;  // rows 8*gi..8*gi+7
  const int gj = t & 7;   // cols 8*gj..8*gj+7
  const int lane = t & 63;

  __shared__ union {
    float wt[128][68];   // P1 staging
    float cw[32][68];    // P2 col partials
    __half Tc[256][72];  // P3 T chunk (XOR-swizzled groups), 36 KB
    float2 mg[2][4096];  // P3 merge, 32 KB
  } u_;
  __shared__ float ev[64];
  __shared__ int cflag;

  // ---- P1a: stage W^T ----
  const float* wm = w + (size_t)m * 64 * 128;
  for (int e = t; e < 64 * 128; e += 1024) {
    int j = e >> 7, d = e & 127;
    u_.wt[d][j] = wm[e];
  }
  if (t < 64) ev[t] = 1.0f;
  __syncthreads();

  // ---- P1b: K tile (8x8/thread), EK = exp(K) ----
  float2 E2[8][4];
  #pragma unroll
  for (int r = 0; r < 8; ++r)
    #pragma unroll
    for (int c = 0; c < 4; ++c) E2[r][c] = make_float2(0.f, 0.f);

  const float* xrow = x + (size_t)nb * 1024 * 128 + (size_t)gi * 8 * 128;
  for (int d = 0; d < 128; d += 4) {
    float2 wr[4][4];
    #pragma unroll
    for (int dd = 0; dd < 4; ++dd) {
      float4 a0 = *(const float4*)&u_.wt[d + dd][8 * gj];
      float4 a1 = *(const float4*)&u_.wt[d + dd][8 * gj + 4];
      wr[dd][0] = make_float2(a0.x, a0.y);
      wr[dd][1] = make_float2(a0.z, a0.w);
      wr[dd][2] = make_float2(a1.x, a1.y);
      wr[dd][3] = make_float2(a1.z, a1.w);
    }
    #pragma unroll
    for (int r = 0; r < 8; ++r) {
      float4 xv = *(const float4*)&xrow[r * 128 + d];
      float xs[4] = {xv.x, xv.y, xv.z, xv.w};
      #pragma unroll
      for (int dd = 0; dd < 4; ++dd)
        #pragma unroll
        for (int c = 0; c < 4; ++c)
          E2[r][c] = pkfma(make_float2(xs[dd], xs[dd]), wr[dd][c], E2[r][c]);
    }
  }
  #pragma unroll
  for (int r = 0; r < 8; ++r)
    #pragma unroll
    for (int c = 0; c < 4; ++c) {
      E2[r][c].x = __expf(E2[r][c].x);
      E2[r][c].y = __expf(E2[r][c].y);
    }
  __syncthreads();

  // ---- P2: Sinkhorn iterations, early exit ----
  float ur[8];
  float2 ep[4];
  for (int it = 0; it < 100; ++it) {
    float4 e0 = *(const float4*)&ev[8 * gj];
    float4 e1 = *(const float4*)&ev[8 * gj + 4];
    ep[0] = make_float2(e0.x, e0.y);
    ep[1] = make_float2(e0.z, e0.w);
    ep[2] = make_float2(e1.x, e1.y);
    ep[3] = make_float2(e1.z, e1.w);
    #pragma unroll
    for (int r = 0; r < 8; ++r) {
      float2 a = make_float2(0.f, 0.f);
      #pragma unroll
      for (int c = 0; c < 4; ++c) a = pkfma(E2[r][c], ep[c], a);
      float sr = a.x + a.y;
      sr = dpp_add<0xB1>(sr);
      sr = dpp_add<0x4E>(sr);
      sr = dpp_add<0x141>(sr);
      ur[r] = 0.0625f * __builtin_amdgcn_rcpf(sr);
    }
    float2 tp[4] = {make_float2(0.f, 0.f), make_float2(0.f, 0.f),
                    make_float2(0.f, 0.f), make_float2(0.f, 0.f)};
    #pragma unroll
    for (int r = 0; r < 8; ++r) {
      float2 uu = make_float2(ur[r], ur[r]);
      #pragma unroll
      for (int c = 0; c < 4; ++c) tp[c] = pkfma(E2[r][c], uu, tp[c]);
    }
    float tv[8] = {tp[0].x, tp[0].y, tp[1].x, tp[1].y,
                   tp[2].x, tp[2].y, tp[3].x, tp[3].y};
    #pragma unroll
    for (int k = 0; k < 8; ++k) {
      tv[k] = dpp_add<0x128>(tv[k]);
      tv[k] = swz16_add(tv[k]);
    }
    if ((lane & 31) < 8) {
      int row = t >> 5;
      *(float4*)&u_.cw[row][8 * gj] = make_float4(tv[0], tv[1], tv[2], tv[3]);
      *(float4*)&u_.cw[row][8 * gj + 4] =
          make_float4(tv[4], tv[5], tv[6], tv[7]);
    }
    __syncthreads();
    if (t < 64) {
      float ss = 0.f;
      #pragma unroll
      for (int p = 0; p < 32; ++p) ss += u_.cw[p][t];
      float evo = ev[t];
      ev[t] = __builtin_amdgcn_rcpf(ss);
      unsigned long long bad = __ballot(fabsf(fmaf(ss, evo, -1.0f)) > 1e-4f);
      if (t == 0) cflag = (bad == 0ULL);
    }
    __syncthreads();
    if (cflag) break;
  }

  // ---- P3: fused out = T^T x, T via LDS in 4 chunks of 256 rows ----
  {
    float4 e0 = *(const float4*)&ev[8 * gj];
    float4 e1 = *(const float4*)&ev[8 * gj + 4];
    ep[0] = make_float2(e0.x, e0.y);
    ep[1] = make_float2(e0.z, e0.w);
    ep[2] = make_float2(e1.x, e1.y);
    ep[3] = make_float2(e1.z, e1.w);
  }
  const int og = t & 15;         // o = 4*og + oc
  const int dg = (t >> 4) & 15;  // d = 8*dg + dd
  const int sg = t >> 8;         // i-segment AND producer-chunk id (== gi>>5)

  float2 acc[4][4];
  #pragma unroll
  for (int oc = 0; oc < 4; ++oc)
    #pragma unroll
    for (int dp = 0; dp < 4; ++dp) acc[oc][dp] = make_float2(0.f, 0.f);

  const float* xb = x + (size_t)nb * 1024 * 128;

  for (int c = 0; c < 4; ++c) {
    __syncthreads();  // previous chunk consumed (or cw dead on first pass)
    if (sg == c) {
      // producer: write this thread's 8x8 T tile, f16, XOR-swizzled groups
      const int rl = 8 * (gi & 31);
      #pragma unroll
      for (int r = 0; r < 8; ++r) {
        const int rr = rl + r;
        const int sw = (rr >> 3) & 7;
        #pragma unroll
        for (int cc = 0; cc < 4; ++cc) {
          float2 tvv;
          tvv.x = E2[r][cc].x * ur[r] * ep[cc].x;
          tvv.y = E2[r][cc].y * ur[r] * ep[cc].y;
          const int grp = 2 * gj + (cc >> 1);
          const int h = (((grp ^ sw) & 15) << 2) | ((cc & 1) << 1);
          *(__half2*)&u_.Tc[rr][h] = __float22half2_rn(tvv);
        }
      }
    }
    __syncthreads();
    // consumer: all threads, 64 i each (segment sg within chunk c)
    const float* xc = xb + (size_t)(256 * c) * 128;
    const int i0 = 64 * sg;
    #pragma unroll 4
    for (int il = i0; il < i0 + 64; ++il) {
      const int sw = (il >> 3) & 7;
      uint2 tw = *(const uint2*)&u_.Tc[il][((og ^ sw) & 15) << 2];
      float2 f01 = __half22float2(*(__half2*)&tw.x);
      float2 f23 = __half22float2(*(__half2*)&tw.y);
      float to[4] = {f01.x, f01.y, f23.x, f23.y};
      float4 x0 = *(const float4*)&xc[(size_t)il * 128 + 8 * dg];
      float4 x1 = *(const float4*)&xc[(size_t)il * 128 + 8 * dg + 4];
      float2 xp[4] = {make_float2(x0.x, x0.y), make_float2(x0.z, x0.w),
                      make_float2(x1.x, x1.y), make_float2(x1.z, x1.w)};
      #pragma unroll
      for (int oc = 0; oc < 4; ++oc) {
        float2 tt = make_float2(to[oc], to[oc]);
        #pragma unroll
        for (int dp = 0; dp < 4; ++dp)
          acc[oc][dp] = pkfma(tt, xp[dp], acc[oc][dp]);
      }
    }
  }

  // ---- merge 4 segments -> seg 0, store ----
  const int r256 = t & 255;
  __syncthreads();
  if (sg & 1) {  // segs 1,3 write
    float2* mp = u_.mg[sg >> 1];
    #pragma unroll
    for (int oc = 0; oc < 4; ++oc)
      #pragma unroll
      for (int dp = 0; dp < 4; ++dp)
        mp[(oc * 4 + dp) * 256 + r256] = acc[oc][dp];
  }
  __syncthreads();
  if (!(sg & 1)) {  // segs 0,2 add
    const float2* mp = u_.mg[sg >> 1];
    #pragma unroll
    for (int oc = 0; oc < 4; ++oc)
      #pragma unroll
      for (int dp = 0; dp < 4; ++dp) {
        float2 v = mp[(oc * 4 + dp) * 256 + r256];
        acc[oc][dp].x += v.x;
        acc[oc][dp].y += v.y;
      }
  }
  __syncthreads();
  if (sg == 2) {
    float2* mp = u_.mg[0];
    #pragma unroll
    for (int oc = 0; oc < 4; ++oc)
      #pragma unroll
      for (int dp = 0; dp < 4; ++dp)
        mp[(oc * 4 + dp) * 256 + r256] = acc[oc][dp];
  }
  __syncthreads();
  if (sg == 0) {
    const float2* mp = u_.mg[0];
    #pragma unroll
    for (int oc = 0; oc < 4; ++oc) {
      float2 p0 = mp[(oc * 4 + 0) * 256 + r256];
      float2 p1 = mp[(oc * 4 + 1) * 256 + r256];
      float2 p2 = mp[(oc * 4 + 2) * 256 + r256];
      float2 p3 = mp[(oc * 4 + 3) * 256 + r256];
      int o = 4 * og + oc;
      float* op = out + ((size_t)nb * 64 + o) * 512 + m * 128 + 8 * dg;
      float4 s0 = make_float4(acc[oc][0].x + p0.x, acc[oc][0].y + p0.y,
                              acc[oc][1].x + p1.x, acc[oc][1].y + p1.y);
      float4 s1 = make_float4(acc[oc][2].x + p2.x, acc[oc][2].y + p2.y,
                              acc[oc][3].x + p3.x, acc[oc][3].y + p3.y);
      *(float4*)op = s0;
      *(float4*)(op + 4) = s1;
    }
  }
}

extern "C" void kernel_launch(void* const* d_in, const int* in_sizes, int n_in,
                              void* d_out, int out_size, void* d_ws, size_t ws_size,
                              hipStream_t stream) {
  const float* x = (const float*)d_in[0];  // [64][1024][128] fp32
  const float* w = (const float*)d_in[1];  // [4][64][128] fp32
  float* out = (float*)d_out;              // [64][64][512] fp32
  ot_fused_kernel<<<256, 1024, 0, stream>>>(x, w, out);
}

// Round 5
// 189.620 us; speedup vs baseline: 1.1268x; 1.1268x over previous
//
#include <hip/hip_runtime.h>
#include <hip/hip_fp16.h>

// Fused Sinkhorn OT. n=64, in_size=1024, in_dim=128, heads=4, out_size=64.
// Single kernel, 256 blocks x 1024 threads (1 block/CU):
//   P1: K-GEMM (fp32 pk-fma, W^T staged LDS) -> EK=exp(K) in regs (8x8/thread)
//   P2: multiplicative Sinkhorn (DPP/swizzle reductions, 2 barriers/iter,
//       early exit tol 1e-4, cap 100)
//   P3: out = T^T x on MFMA f32_16x16x32_f16. Per 256-row chunk: stage x->f16
//       LDS Xh[d][i] + T->f16 LDS To[o][i] (both XOR-swizzled 16B i-groups),
//       16 waves each own one (o-tile, d-tile-pair); acc persists -> no merge.

typedef _Float16 half8 __attribute__((ext_vector_type(8)));
typedef float f32x4 __attribute__((ext_vector_type(4)));

__device__ __forceinline__ float2 pkfma(float2 a, float2 b, float2 c) {
  return make_float2(fmaf(a.x, b.x, c.x), fmaf(a.y, b.y, c.y));
}

template <int CTRL>
__device__ __forceinline__ float dpp_add(float v) {
  return v + __int_as_float(__builtin_amdgcn_update_dpp(
                 0, __float_as_int(v), CTRL, 0xf, 0xf, true));
}
__device__ __forceinline__ float swz16_add(float v) {
  return v + __int_as_float(
                 __builtin_amdgcn_ds_swizzle(__float_as_int(v), 0x401F));
}

// XCD-aware batch map: 4 heads of one nb + 8 nb per XCD (4 MB x-slice = L2).
__device__ __forceinline__ void batch_map(int bb, int& nb, int& m) {
  int k = bb >> 3;
  nb = 8 * (bb & 7) + (k >> 2);
  m = k & 3;
}

__global__ __launch_bounds__(1024, 4) void ot_fused_kernel(
    const float* __restrict__ x, const float* __restrict__ w,
    float* __restrict__ out) {
  int nb, m;
  batch_map(blockIdx.x, nb, m);
  const int t = threadIdx.x;
  const int gi = t >> 3;  // rows 8*gi..8*gi+7
  const int gj = t & 7;   // cols 8*gj..8*gj+7
  const int lane = t & 63;

  __shared__ union {
    float wt[128][68];  // P1 staging
    float cw[32][68];   // P2 col partials
    struct {
      __half Xh[128 * 256];  // P3 x chunk, f16, [d][i-local] XOR-swizzled
      __half To[64 * 256];   // P3 T chunk, f16, [o][i-local] XOR-swizzled
    } p3;                    // 96 KB
  } u_;
  __shared__ float ev[64];
  __shared__ int cflag;

  // ---- P1a: stage W^T ----
  const float* wm = w + (size_t)m * 64 * 128;
  for (int e = t; e < 64 * 128; e += 1024) {
    int j = e >> 7, d = e & 127;
    u_.wt[d][j] = wm[e];
  }
  if (t < 64) ev[t] = 1.0f;
  __syncthreads();

  // ---- P1b: K tile (8x8/thread), EK = exp(K) ----
  float2 E2[8][4];
  #pragma unroll
  for (int r = 0; r < 8; ++r)
    #pragma unroll
    for (int c = 0; c < 4; ++c) E2[r][c] = make_float2(0.f, 0.f);

  const float* xrow = x + (size_t)nb * 1024 * 128 + (size_t)gi * 8 * 128;
  for (int d = 0; d < 128; d += 4) {
    float2 wr[4][4];
    #pragma unroll
    for (int dd = 0; dd < 4; ++dd) {
      float4 a0 = *(const float4*)&u_.wt[d + dd][8 * gj];
      float4 a1 = *(const float4*)&u_.wt[d + dd][8 * gj + 4];
      wr[dd][0] = make_float2(a0.x, a0.y);
      wr[dd][1] = make_float2(a0.z, a0.w);
      wr[dd][2] = make_float2(a1.x, a1.y);
      wr[dd][3] = make_float2(a1.z, a1.w);
    }
    #pragma unroll
    for (int r = 0; r < 8; ++r) {
      float4 xv = *(const float4*)&xrow[r * 128 + d];
      float xs[4] = {xv.x, xv.y, xv.z, xv.w};
      #pragma unroll
      for (int dd = 0; dd < 4; ++dd)
        #pragma unroll
        for (int c = 0; c < 4; ++c)
          E2[r][c] = pkfma(make_float2(xs[dd], xs[dd]), wr[dd][c], E2[r][c]);
    }
  }
  #pragma unroll
  for (int r = 0; r < 8; ++r)
    #pragma unroll
    for (int c = 0; c < 4; ++c) {
      E2[r][c].x = __expf(E2[r][c].x);
      E2[r][c].y = __expf(E2[r][c].y);
    }
  __syncthreads();

  // ---- P2: Sinkhorn iterations, early exit ----
  float ur[8];
  float2 ep[4];
  for (int it = 0; it < 100; ++it) {
    float4 e0 = *(const float4*)&ev[8 * gj];
    float4 e1 = *(const float4*)&ev[8 * gj + 4];
    ep[0] = make_float2(e0.x, e0.y);
    ep[1] = make_float2(e0.z, e0.w);
    ep[2] = make_float2(e1.x, e1.y);
    ep[3] = make_float2(e1.z, e1.w);
    #pragma unroll
    for (int r = 0; r < 8; ++r) {
      float2 a = make_float2(0.f, 0.f);
      #pragma unroll
      for (int c = 0; c < 4; ++c) a = pkfma(E2[r][c], ep[c], a);
      float sr = a.x + a.y;
      sr = dpp_add<0xB1>(sr);
      sr = dpp_add<0x4E>(sr);
      sr = dpp_add<0x141>(sr);
      ur[r] = 0.0625f * __builtin_amdgcn_rcpf(sr);
    }
    float2 tp[4] = {make_float2(0.f, 0.f), make_float2(0.f, 0.f),
                    make_float2(0.f, 0.f), make_float2(0.f, 0.f)};
    #pragma unroll
    for (int r = 0; r < 8; ++r) {
      float2 uu = make_float2(ur[r], ur[r]);
      #pragma unroll
      for (int c = 0; c < 4; ++c) tp[c] = pkfma(E2[r][c], uu, tp[c]);
    }
    float tv[8] = {tp[0].x, tp[0].y, tp[1].x, tp[1].y,
                   tp[2].x, tp[2].y, tp[3].x, tp[3].y};
    #pragma unroll
    for (int k = 0; k < 8; ++k) {
      tv[k] = dpp_add<0x128>(tv[k]);
      tv[k] = swz16_add(tv[k]);
    }
    if ((lane & 31) < 8) {
      int row = t >> 5;
      *(float4*)&u_.cw[row][8 * gj] = make_float4(tv[0], tv[1], tv[2], tv[3]);
      *(float4*)&u_.cw[row][8 * gj + 4] =
          make_float4(tv[4], tv[5], tv[6], tv[7]);
    }
    __syncthreads();
    if (t < 64) {
      float ss = 0.f;
      #pragma unroll
      for (int p = 0; p < 32; ++p) ss += u_.cw[p][t];
      float evo = ev[t];
      ev[t] = __builtin_amdgcn_rcpf(ss);
      unsigned long long bad = __ballot(fabsf(fmaf(ss, evo, -1.0f)) > 1e-4f);
      if (t == 0) cflag = (bad == 0ULL);
    }
    __syncthreads();
    if (cflag) break;
  }

  // ---- P3: out = T^T x via MFMA 16x16x32 f16 ----
  {
    float4 e0 = *(const float4*)&ev[8 * gj];
    float4 e1 = *(const float4*)&ev[8 * gj + 4];
    ep[0] = make_float2(e0.x, e0.y);
    ep[1] = make_float2(e0.z, e0.w);
    ep[2] = make_float2(e1.x, e1.y);
    ep[3] = make_float2(e1.z, e1.w);
  }
  // ET = EK * ur * ev, in place (f32)
  #pragma unroll
  for (int r = 0; r < 8; ++r) {
    float2 uu = make_float2(ur[r], ur[r]);
    #pragma unroll
    for (int c = 0; c < 4; ++c) {
      E2[r][c].x = E2[r][c].x * uu.x * ep[c].x;
      E2[r][c].y = E2[r][c].y * uu.y * ep[c].y;
    }
  }

  const int a5 = t >> 5;    // 0..31: x-stager i-group
  const int dgx = t & 31;   // x-stager d-quad
  const int wvw = t >> 6;   // wave 0..15
  const int ml = lane & 15;
  const int kq = lane >> 4;     // k-quad 0..3
  const int ota = wvw & 3;      // o-tile 0..3 (o = 16*ota + ml rows of A)
  const int dtb = wvw >> 2;     // 0..3 -> d-tiles 2dtb, 2dtb+1
  const int oA = 16 * ota + ml;
  const int d0 = 32 * dtb + ml;
  const int d1 = d0 + 16;

  f32x4 acc0 = {0.f, 0.f, 0.f, 0.f}, acc1 = {0.f, 0.f, 0.f, 0.f};
  const float* xb = x + (size_t)nb * 1024 * 128;

  for (int c = 0; c < 4; ++c) {
    __syncthreads();  // previous chunk consumed / P2 LDS dead
    // -- stage x chunk: rows 256c+8*a5..+7, cols 4*dgx..+3, f32->f16,
    //    in-register transpose to Xh[d][i-local] --
    {
      const float* xs = xb + (size_t)(256 * c + 8 * a5) * 128 + 4 * dgx;
      float xr[8][4];
      #pragma unroll
      for (int r = 0; r < 8; ++r) {
        float4 v = *(const float4*)(xs + (size_t)r * 128);
        xr[r][0] = v.x; xr[r][1] = v.y; xr[r][2] = v.z; xr[r][3] = v.w;
      }
      #pragma unroll
      for (int k = 0; k < 4; ++k) {
        __half2 hh[4];
        #pragma unroll
        for (int q = 0; q < 4; ++q)
          hh[q] = __float22half2_rn(
              make_float2(xr[2 * q][k], xr[2 * q + 1][k]));
        const int d = 4 * dgx + k;
        const int pos = (a5 ^ (d & 31)) & 31;
        *(uint4*)&u_.p3.Xh[d * 256 + pos * 8] = *(uint4*)hh;
      }
    }
    // -- producer: threads owning this chunk's rows write To[o][i-local] --
    if ((t >> 8) == c) {
      const int g = gi & 31;  // i-local group
      #pragma unroll
      for (int co = 0; co < 8; ++co) {
        float tvv[8];
        #pragma unroll
        for (int r = 0; r < 8; ++r)
          tvv[r] = (co & 1) ? E2[r][co >> 1].y : E2[r][co >> 1].x;
        __half2 hh[4];
        #pragma unroll
        for (int q = 0; q < 4; ++q)
          hh[q] = __float22half2_rn(make_float2(tvv[2 * q], tvv[2 * q + 1]));
        const int o = 8 * gj + co;
        const int pos = (g ^ (o & 31)) & 31;
        *(uint4*)&u_.p3.To[o * 256 + pos * 8] = *(uint4*)hh;
      }
    }
    __syncthreads();
    // -- MFMA: 8 K-steps of 32, two d-tiles per wave --
    #pragma unroll
    for (int s = 0; s < 8; ++s) {
      const int gk = 4 * s + kq;
      half8 af = *(const half8*)&u_.p3.To[oA * 256 + ((gk ^ (oA & 31)) & 31) * 8];
      half8 b0 = *(const half8*)&u_.p3.Xh[d0 * 256 + ((gk ^ (d0 & 31)) & 31) * 8];
      half8 b1 = *(const half8*)&u_.p3.Xh[d1 * 256 + ((gk ^ (d1 & 31)) & 31) * 8];
      acc0 = __builtin_amdgcn_mfma_f32_16x16x32_f16(af, b0, acc0, 0, 0, 0);
      acc1 = __builtin_amdgcn_mfma_f32_16x16x32_f16(af, b1, acc1, 0, 0, 0);
    }
  }

  // ---- store: C[row=o][col=d], row=4*kq+reg within tile, col=ml ----
  #pragma unroll
  for (int rg = 0; rg < 4; ++rg) {
    const int o = 16 * ota + 4 * kq + rg;
    float* op = out + ((size_t)nb * 64 + o) * 512 + m * 128;
    op[d0] = acc0[rg];
    op[d1] = acc1[rg];
  }
}

extern "C" void kernel_launch(void* const* d_in, const int* in_sizes, int n_in,
                              void* d_out, int out_size, void* d_ws, size_t ws_size,
                              hipStream_t stream) {
  const float* x = (const float*)d_in[0];  // [64][1024][128] fp32
  const float* w = (const float*)d_in[1];  // [4][64][128] fp32
  float* out = (float*)d_out;              // [64][64][512] fp32
  ot_fused_kernel<<<256, 1024, 0, stream>>>(x, w, out);
}

// Round 6
// 176.928 us; speedup vs baseline: 1.2076x; 1.0717x over previous
//
#include <hip/hip_runtime.h>
#include <hip/hip_fp16.h>

// Fused Sinkhorn OT. n=64, in_size=1024, in_dim=128, heads=4, out_size=64.
// Single kernel, 256 blocks x 1024 threads (1 block/CU):
//   P1: K-GEMM (fp32 pk-fma, W^T staged LDS) -> EK=exp(K) in regs (8x8/thread)
//   P2: multiplicative Sinkhorn (DPP/swizzle reductions, 2 barriers/iter,
//       early exit tol 1e-4, cap 100)
//   P3: out = T^T x on MFMA f32_16x16x32_f16, software-pipelined:
//       T pre-packed to f16 regs (hhT), next x chunk prefetched into 8 float4
//       regs issued AFTER the post-staging barrier (completes under MFMA);
//       Xh swizzle includes ^((d>>2)&7) so stager writes and B-reads both sit
//       at the 8-lane/bank-quad b128 structural floor.

typedef _Float16 half8 __attribute__((ext_vector_type(8)));
typedef float f32x4 __attribute__((ext_vector_type(4)));

__device__ __forceinline__ float2 pkfma(float2 a, float2 b, float2 c) {
  return make_float2(fmaf(a.x, b.x, c.x), fmaf(a.y, b.y, c.y));
}

template <int CTRL>
__device__ __forceinline__ float dpp_add(float v) {
  return v + __int_as_float(__builtin_amdgcn_update_dpp(
                 0, __float_as_int(v), CTRL, 0xf, 0xf, true));
}
__device__ __forceinline__ float swz16_add(float v) {
  return v + __int_as_float(
                 __builtin_amdgcn_ds_swizzle(__float_as_int(v), 0x401F));
}

// XCD-aware batch map: 4 heads of one nb + 8 nb per XCD (4 MB x-slice = L2).
__device__ __forceinline__ void batch_map(int bb, int& nb, int& m) {
  int k = bb >> 3;
  nb = 8 * (bb & 7) + (k >> 2);
  m = k & 3;
}

__global__ __launch_bounds__(1024, 4) void ot_fused_kernel(
    const float* __restrict__ x, const float* __restrict__ w,
    float* __restrict__ out) {
  int nb, m;
  batch_map(blockIdx.x, nb, m);
  const int t = threadIdx.x;
  const int gi = t >> 3;  // rows 8*gi..8*gi+7
  const int gj = t & 7;   // cols 8*gj..8*gj+7
  const int lane = t & 63;

  __shared__ union {
    float wt[128][68];  // P1 staging
    float cw[32][68];   // P2 col partials
    struct {
      __half Xh[128 * 256];  // P3 x chunk, f16, [d][i-local] swizzled
      __half To[64 * 256];   // P3 T chunk, f16, [o][i-local] swizzled
    } p3;                    // 96 KB
  } u_;
  __shared__ float ev[64];
  __shared__ int cflag;

  // ---- P1a: stage W^T ----
  const float* wm = w + (size_t)m * 64 * 128;
  for (int e = t; e < 64 * 128; e += 1024) {
    int j = e >> 7, d = e & 127;
    u_.wt[d][j] = wm[e];
  }
  if (t < 64) ev[t] = 1.0f;
  __syncthreads();

  // ---- P1b: K tile (8x8/thread), EK = exp(K) ----
  float2 E2[8][4];
  #pragma unroll
  for (int r = 0; r < 8; ++r)
    #pragma unroll
    for (int c = 0; c < 4; ++c) E2[r][c] = make_float2(0.f, 0.f);

  const float* xrow = x + (size_t)nb * 1024 * 128 + (size_t)gi * 8 * 128;
  for (int d = 0; d < 128; d += 4) {
    float2 wr[4][4];
    #pragma unroll
    for (int dd = 0; dd < 4; ++dd) {
      float4 a0 = *(const float4*)&u_.wt[d + dd][8 * gj];
      float4 a1 = *(const float4*)&u_.wt[d + dd][8 * gj + 4];
      wr[dd][0] = make_float2(a0.x, a0.y);
      wr[dd][1] = make_float2(a0.z, a0.w);
      wr[dd][2] = make_float2(a1.x, a1.y);
      wr[dd][3] = make_float2(a1.z, a1.w);
    }
    #pragma unroll
    for (int r = 0; r < 8; ++r) {
      float4 xv = *(const float4*)&xrow[r * 128 + d];
      float xs[4] = {xv.x, xv.y, xv.z, xv.w};
      #pragma unroll
      for (int dd = 0; dd < 4; ++dd)
        #pragma unroll
        for (int c = 0; c < 4; ++c)
          E2[r][c] = pkfma(make_float2(xs[dd], xs[dd]), wr[dd][c], E2[r][c]);
    }
  }
  #pragma unroll
  for (int r = 0; r < 8; ++r)
    #pragma unroll
    for (int c = 0; c < 4; ++c) {
      E2[r][c].x = __expf(E2[r][c].x);
      E2[r][c].y = __expf(E2[r][c].y);
    }
  __syncthreads();

  // ---- P2: Sinkhorn iterations, early exit ----
  float ur[8];
  float2 ep[4];
  for (int it = 0; it < 100; ++it) {
    float4 e0 = *(const float4*)&ev[8 * gj];
    float4 e1 = *(const float4*)&ev[8 * gj + 4];
    ep[0] = make_float2(e0.x, e0.y);
    ep[1] = make_float2(e0.z, e0.w);
    ep[2] = make_float2(e1.x, e1.y);
    ep[3] = make_float2(e1.z, e1.w);
    #pragma unroll
    for (int r = 0; r < 8; ++r) {
      float2 a = make_float2(0.f, 0.f);
      #pragma unroll
      for (int c = 0; c < 4; ++c) a = pkfma(E2[r][c], ep[c], a);
      float sr = a.x + a.y;
      sr = dpp_add<0xB1>(sr);
      sr = dpp_add<0x4E>(sr);
      sr = dpp_add<0x141>(sr);
      ur[r] = 0.0625f * __builtin_amdgcn_rcpf(sr);
    }
    float2 tp[4] = {make_float2(0.f, 0.f), make_float2(0.f, 0.f),
                    make_float2(0.f, 0.f), make_float2(0.f, 0.f)};
    #pragma unroll
    for (int r = 0; r < 8; ++r) {
      float2 uu = make_float2(ur[r], ur[r]);
      #pragma unroll
      for (int c = 0; c < 4; ++c) tp[c] = pkfma(E2[r][c], uu, tp[c]);
    }
    float tv[8] = {tp[0].x, tp[0].y, tp[1].x, tp[1].y,
                   tp[2].x, tp[2].y, tp[3].x, tp[3].y};
    #pragma unroll
    for (int k = 0; k < 8; ++k) {
      tv[k] = dpp_add<0x128>(tv[k]);
      tv[k] = swz16_add(tv[k]);
    }
    if ((lane & 31) < 8) {
      int row = t >> 5;
      *(float4*)&u_.cw[row][8 * gj] = make_float4(tv[0], tv[1], tv[2], tv[3]);
      *(float4*)&u_.cw[row][8 * gj + 4] =
          make_float4(tv[4], tv[5], tv[6], tv[7]);
    }
    __syncthreads();
    if (t < 64) {
      float ss = 0.f;
      #pragma unroll
      for (int p = 0; p < 32; ++p) ss += u_.cw[p][t];
      float evo = ev[t];
      ev[t] = __builtin_amdgcn_rcpf(ss);
      unsigned long long bad = __ballot(fabsf(fmaf(ss, evo, -1.0f)) > 1e-4f);
      if (t == 0) cflag = (bad == 0ULL);
    }
    __syncthreads();
    if (cflag) break;
  }

  // ---- P3 prologue: scale T, pack to f16 regs (o-major, row-pairs) ----
  {
    float4 e0 = *(const float4*)&ev[8 * gj];
    float4 e1 = *(const float4*)&ev[8 * gj + 4];
    ep[0] = make_float2(e0.x, e0.y);
    ep[1] = make_float2(e0.z, e0.w);
    ep[2] = make_float2(e1.x, e1.y);
    ep[3] = make_float2(e1.z, e1.w);
  }
  #pragma unroll
  for (int r = 0; r < 8; ++r) {
    float2 uu = make_float2(ur[r], ur[r]);
    #pragma unroll
    for (int c = 0; c < 4; ++c) {
      E2[r][c].x = E2[r][c].x * uu.x * ep[c].x;
      E2[r][c].y = E2[r][c].y * uu.y * ep[c].y;
    }
  }
  __half2 hhT[8][4];  // hhT[co][q] = (T[2q][co], T[2q+1][co]), E2 dead after
  #pragma unroll
  for (int co = 0; co < 8; ++co)
    #pragma unroll
    for (int q = 0; q < 4; ++q) {
      float va = (co & 1) ? E2[2 * q][co >> 1].y : E2[2 * q][co >> 1].x;
      float vb =
          (co & 1) ? E2[2 * q + 1][co >> 1].y : E2[2 * q + 1][co >> 1].x;
      hhT[co][q] = __float22half2_rn(make_float2(va, vb));
    }

  // ---- P3: out = T^T x via MFMA, register-prefetch pipeline ----
  const int a5 = t >> 5;   // x-stager i-group (0..31)
  const int dgx = t & 31;  // x-stager d-quad
  const int wvw = t >> 6;  // wave 0..15
  const int ml = lane & 15;
  const int kq = lane >> 4;  // k-quad 0..3
  const int ota = wvw & 3;   // o-tile
  const int dtb = wvw >> 2;  // d-tile pair
  const int oA = 16 * ota + ml;
  const int d0 = 32 * dtb + ml;
  const int d1 = d0 + 16;
  const int pA = ((0 ^ (oA & 31)) & 31);  // base; recomputed with gk below

  f32x4 acc0 = {0.f, 0.f, 0.f, 0.f}, acc1 = {0.f, 0.f, 0.f, 0.f};
  const float* xb = x + (size_t)nb * 1024 * 128;

  float4 xpre[8];
  {
    const float* xs = xb + (size_t)(8 * a5) * 128 + 4 * dgx;
    #pragma unroll
    for (int r = 0; r < 8; ++r) xpre[r] = *(const float4*)(xs + r * 128);
  }

  for (int c = 0; c < 4; ++c) {
    __syncthreads();  // prev chunk consumed / P2 LDS dead
    // stage x chunk from prefetch regs: f32->f16, [d][i-local]
    #pragma unroll
    for (int k = 0; k < 4; ++k) {
      __half2 hh[4];
      #pragma unroll
      for (int q = 0; q < 4; ++q) {
        const float* pa = (const float*)&xpre[2 * q];
        const float* pb = (const float*)&xpre[2 * q + 1];
        hh[q] = __float22half2_rn(make_float2(pa[k], pb[k]));
      }
      const int d = 4 * dgx + k;
      const int pos = (a5 ^ (d & 31) ^ ((d >> 2) & 7)) & 31;
      *(uint4*)&u_.p3.Xh[d * 256 + pos * 8] = *(uint4*)hh;
    }
    // producers for this chunk write To from hhT regs
    if ((t >> 8) == c) {
      const int g = gi & 31;
      #pragma unroll
      for (int co = 0; co < 8; ++co) {
        const int o = 8 * gj + co;
        const int pos = (g ^ (o & 31)) & 31;
        *(uint4*)&u_.p3.To[o * 256 + pos * 8] = *(uint4*)&hhT[co][0];
      }
    }
    __syncthreads();
    // issue next chunk's prefetch AFTER the barrier: completes under MFMA,
    // drained by the next chunk-top barrier's vmcnt(0).
    if (c < 3) {
      const float* xs = xb + (size_t)(256 * (c + 1) + 8 * a5) * 128 + 4 * dgx;
      #pragma unroll
      for (int r = 0; r < 8; ++r) xpre[r] = *(const float4*)(xs + r * 128);
    }
    // MFMA: 8 K-steps of 32, two d-tiles per wave
    #pragma unroll
    for (int s = 0; s < 8; ++s) {
      const int gk = 4 * s + kq;
      half8 af =
          *(const half8*)&u_.p3.To[oA * 256 + ((gk ^ (oA & 31)) & 31) * 8];
      const int pb0 = (gk ^ (d0 & 31) ^ ((d0 >> 2) & 7)) & 31;
      const int pb1 = (gk ^ (d1 & 31) ^ ((d1 >> 2) & 7)) & 31;
      half8 b0 = *(const half8*)&u_.p3.Xh[d0 * 256 + pb0 * 8];
      half8 b1 = *(const half8*)&u_.p3.Xh[d1 * 256 + pb1 * 8];
      acc0 = __builtin_amdgcn_mfma_f32_16x16x32_f16(af, b0, acc0, 0, 0, 0);
      acc1 = __builtin_amdgcn_mfma_f32_16x16x32_f16(af, b1, acc1, 0, 0, 0);
    }
  }
  (void)pA;

  // ---- store: C tile row = o (4*kq+rg), col = d (ml) ----
  #pragma unroll
  for (int rg = 0; rg < 4; ++rg) {
    const int o = 16 * ota + 4 * kq + rg;
    float* op = out + ((size_t)nb * 64 + o) * 512 + m * 128;
    op[d0] = acc0[rg];
    op[d1] = acc1[rg];
  }
}

extern "C" void kernel_launch(void* const* d_in, const int* in_sizes, int n_in,
                              void* d_out, int out_size, void* d_ws, size_t ws_size,
                              hipStream_t stream) {
  const float* x = (const float*)d_in[0];  // [64][1024][128] fp32
  const float* w = (const float*)d_in[1];  // [4][64][128] fp32
  float* out = (float*)d_out;              // [64][64][512] fp32
  ot_fused_kernel<<<256, 1024, 0, stream>>>(x, w, out);
}

// Round 7
// 174.620 us; speedup vs baseline: 1.2236x; 1.0132x over previous
//
#include <hip/hip_runtime.h>
#include <hip/hip_fp16.h>

// Fused Sinkhorn OT. n=64, in_size=1024, in_dim=128, heads=4, out_size=64.
// Single kernel, 256 blocks x 1024 threads (1 block/CU):
//   P1: K-GEMM (fp32 pk-fma, W^T staged LDS) -> EK=exp(K) in regs (8x8/thread)
//   P2: multiplicative Sinkhorn (DPP/swizzle/xor32 reductions, early exit
//       tol 1e-4, cap 100); wave0 final-reduces 16 partials (not 32)
//   P3: out = T^T x on MFMA f32_16x16x32_f16, DOUBLE-BUFFERED 128-row chunks:
//       per chunk: issue next x loads -> MFMA current buf -> cvt+stage next
//       buf -> one barrier. T pre-packed to f16 regs (hhT, 16 VGPRs); no other
//       state crosses barriers (kills R6's scratch spills).

typedef _Float16 half8 __attribute__((ext_vector_type(8)));
typedef float f32x4 __attribute__((ext_vector_type(4)));

__device__ __forceinline__ float2 pkfma(float2 a, float2 b, float2 c) {
  return make_float2(fmaf(a.x, b.x, c.x), fmaf(a.y, b.y, c.y));
}

template <int CTRL>
__device__ __forceinline__ float dpp_add(float v) {
  return v + __int_as_float(__builtin_amdgcn_update_dpp(
                 0, __float_as_int(v), CTRL, 0xf, 0xf, true));
}
__device__ __forceinline__ float swz16_add(float v) {
  return v + __int_as_float(
                 __builtin_amdgcn_ds_swizzle(__float_as_int(v), 0x401F));
}

// XCD-aware batch map: 4 heads of one nb + 8 nb per XCD (4 MB x-slice = L2).
__device__ __forceinline__ void batch_map(int bb, int& nb, int& m) {
  int k = bb >> 3;
  nb = 8 * (bb & 7) + (k >> 2);
  m = k & 3;
}

__global__ __launch_bounds__(1024, 4) void ot_fused_kernel(
    const float* __restrict__ x, const float* __restrict__ w,
    float* __restrict__ out) {
  int nb, m;
  batch_map(blockIdx.x, nb, m);
  const int t = threadIdx.x;
  const int gi = t >> 3;  // rows 8*gi..8*gi+7
  const int gj = t & 7;   // cols 8*gj..8*gj+7
  const int lane = t & 63;
  const int wvw = t >> 6;  // wave 0..15

  __shared__ union {
    float wt[128][68];  // P1 staging
    float cw[16][68];   // P2 per-wave col partials (16 after xor32)
    struct {
      __half Xh[2][128 * 128];  // P3 x chunks, f16, [d][i-local] swizzled
      __half To[2][64 * 128];   // P3 T chunks, f16, [o][i-local] swizzled
    } p3;                       // 96 KB
  } u_;
  __shared__ float ev[64];
  __shared__ int cflag;

  // ---- P1a: stage W^T ----
  const float* wm = w + (size_t)m * 64 * 128;
  for (int e = t; e < 64 * 128; e += 1024) {
    int j = e >> 7, d = e & 127;
    u_.wt[d][j] = wm[e];
  }
  if (t < 64) ev[t] = 1.0f;
  __syncthreads();

  // ---- P1b: K tile (8x8/thread), EK = exp(K) ----
  float2 E2[8][4];
  #pragma unroll
  for (int r = 0; r < 8; ++r)
    #pragma unroll
    for (int c = 0; c < 4; ++c) E2[r][c] = make_float2(0.f, 0.f);

  const float* xrow = x + (size_t)nb * 1024 * 128 + (size_t)gi * 8 * 128;
  for (int d = 0; d < 128; d += 4) {
    float2 wr[4][4];
    #pragma unroll
    for (int dd = 0; dd < 4; ++dd) {
      float4 a0 = *(const float4*)&u_.wt[d + dd][8 * gj];
      float4 a1 = *(const float4*)&u_.wt[d + dd][8 * gj + 4];
      wr[dd][0] = make_float2(a0.x, a0.y);
      wr[dd][1] = make_float2(a0.z, a0.w);
      wr[dd][2] = make_float2(a1.x, a1.y);
      wr[dd][3] = make_float2(a1.z, a1.w);
    }
    #pragma unroll
    for (int r = 0; r < 8; ++r) {
      float4 xv = *(const float4*)&xrow[r * 128 + d];
      float xs[4] = {xv.x, xv.y, xv.z, xv.w};
      #pragma unroll
      for (int dd = 0; dd < 4; ++dd)
        #pragma unroll
        for (int c = 0; c < 4; ++c)
          E2[r][c] = pkfma(make_float2(xs[dd], xs[dd]), wr[dd][c], E2[r][c]);
    }
  }
  #pragma unroll
  for (int r = 0; r < 8; ++r)
    #pragma unroll
    for (int c = 0; c < 4; ++c) {
      E2[r][c].x = __expf(E2[r][c].x);
      E2[r][c].y = __expf(E2[r][c].y);
    }
  __syncthreads();

  // ---- P2: Sinkhorn iterations, early exit ----
  float ur[8];
  float2 ep[4];
  for (int it = 0; it < 100; ++it) {
    float4 e0 = *(const float4*)&ev[8 * gj];
    float4 e1 = *(const float4*)&ev[8 * gj + 4];
    ep[0] = make_float2(e0.x, e0.y);
    ep[1] = make_float2(e0.z, e0.w);
    ep[2] = make_float2(e1.x, e1.y);
    ep[3] = make_float2(e1.z, e1.w);
    // (A) row sums + DPP butterfly over gj
    #pragma unroll
    for (int r = 0; r < 8; ++r) {
      float2 a = make_float2(0.f, 0.f);
      #pragma unroll
      for (int c = 0; c < 4; ++c) a = pkfma(E2[r][c], ep[c], a);
      float sr = a.x + a.y;
      sr = dpp_add<0xB1>(sr);
      sr = dpp_add<0x4E>(sr);
      sr = dpp_add<0x141>(sr);
      ur[r] = 0.0625f * __builtin_amdgcn_rcpf(sr);
    }
    // (B) col partials over 8 rows; reduce xor8+xor16+xor32 -> wave partial
    float2 tp[4] = {make_float2(0.f, 0.f), make_float2(0.f, 0.f),
                    make_float2(0.f, 0.f), make_float2(0.f, 0.f)};
    #pragma unroll
    for (int r = 0; r < 8; ++r) {
      float2 uu = make_float2(ur[r], ur[r]);
      #pragma unroll
      for (int c = 0; c < 4; ++c) tp[c] = pkfma(E2[r][c], uu, tp[c]);
    }
    float tv[8] = {tp[0].x, tp[0].y, tp[1].x, tp[1].y,
                   tp[2].x, tp[2].y, tp[3].x, tp[3].y};
    #pragma unroll
    for (int k = 0; k < 8; ++k) {
      tv[k] = dpp_add<0x128>(tv[k]);
      tv[k] = swz16_add(tv[k]);
      tv[k] += __shfl_xor(tv[k], 32, 64);
    }
    if (lane < 8) {  // lane == gj: cols 8*lane..8*lane+7
      *(float4*)&u_.cw[wvw][8 * lane] =
          make_float4(tv[0], tv[1], tv[2], tv[3]);
      *(float4*)&u_.cw[wvw][8 * lane + 4] =
          make_float4(tv[4], tv[5], tv[6], tv[7]);
    }
    __syncthreads();
    // (C) final reduce of 16 wave partials + convergence check (wave 0)
    if (t < 64) {
      float ss = 0.f;
      #pragma unroll
      for (int p = 0; p < 16; ++p) ss += u_.cw[p][t];
      float evo = ev[t];
      ev[t] = __builtin_amdgcn_rcpf(ss);
      unsigned long long bad = __ballot(fabsf(fmaf(ss, evo, -1.0f)) > 1e-4f);
      if (t == 0) cflag = (bad == 0ULL);
    }
    __syncthreads();
    if (cflag) break;
  }

  // ---- P3 prologue: scale T, pack to f16 regs hhT (E2 dies here) ----
  {
    float4 e0 = *(const float4*)&ev[8 * gj];
    float4 e1 = *(const float4*)&ev[8 * gj + 4];
    ep[0] = make_float2(e0.x, e0.y);
    ep[1] = make_float2(e0.z, e0.w);
    ep[2] = make_float2(e1.x, e1.y);
    ep[3] = make_float2(e1.z, e1.w);
  }
  #pragma unroll
  for (int r = 0; r < 8; ++r) {
    float2 uu = make_float2(ur[r], ur[r]);
    #pragma unroll
    for (int c = 0; c < 4; ++c) {
      E2[r][c].x = E2[r][c].x * uu.x * ep[c].x;
      E2[r][c].y = E2[r][c].y * uu.y * ep[c].y;
    }
  }
  __half2 hhT[8][4];  // hhT[co][q] = (T[2q][co], T[2q+1][co])
  #pragma unroll
  for (int co = 0; co < 8; ++co)
    #pragma unroll
    for (int q = 0; q < 4; ++q) {
      float va = (co & 1) ? E2[2 * q][co >> 1].y : E2[2 * q][co >> 1].x;
      float vb =
          (co & 1) ? E2[2 * q + 1][co >> 1].y : E2[2 * q + 1][co >> 1].x;
      hhT[co][q] = __float22half2_rn(make_float2(va, vb));
    }

  // ---- P3: out = T^T x via MFMA, double-buffered 128-row chunks ----
  const int ig4 = t >> 5;    // i-quad group 0..31 (rows 4*ig4..+3 of chunk)
  const int dq = t & 31;     // d-quad
  const int o8w = ig4 >> 1;  // logical i-oct of this stager
  const int hw = ig4 & 1;    // half within oct
  const int ml = lane & 15;
  const int kq = lane >> 4;
  const int ota = wvw & 3;
  const int dtb = wvw >> 2;
  const int oA = 16 * ota + ml;
  const int d0 = 32 * dtb + ml;
  const int d1 = d0 + 16;
  const int swA = oA & 15;
  const int swB0 = ((d0 >> 2) & 15) ^ ((d0 & 3) << 2);
  const int swB1 = ((d1 >> 2) & 15) ^ ((d1 & 3) << 2);

  f32x4 acc0 = {0.f, 0.f, 0.f, 0.f}, acc1 = {0.f, 0.f, 0.f, 0.f};
  const float* xb = x + (size_t)nb * 1024 * 128;

  auto stage_x = [&](int p, const float4* xv) {
    #pragma unroll
    for (int k = 0; k < 4; ++k) {
      const float* f0 = (const float*)&xv[0];
      const float* f1 = (const float*)&xv[1];
      const float* f2 = (const float*)&xv[2];
      const float* f3 = (const float*)&xv[3];
      __half2 hp[2];
      hp[0] = __float22half2_rn(make_float2(f0[k], f1[k]));
      hp[1] = __float22half2_rn(make_float2(f2[k], f3[k]));
      const int d = 4 * dq + k;
      const int pos = (o8w ^ (dq & 15) ^ (k << 2)) & 15;
      *(uint2*)&u_.p3.Xh[p][d * 128 + pos * 8 + hw * 4] = *(uint2*)hp;
    }
  };
  auto stage_T = [&](int c, int p) {
    if ((t >> 7) == c) {  // this thread's 8 rows live in chunk c
      const int g = gi & 15;
      #pragma unroll
      for (int co = 0; co < 8; ++co) {
        const int o = 8 * gj + co;
        const int pos = (g ^ (o & 15)) & 15;
        *(uint4*)&u_.p3.To[p][o * 128 + pos * 8] = *(const uint4*)&hhT[co][0];
      }
    }
  };

  // prologue: stage chunk 0 into buf 0
  {
    float4 xv[4];
    const float* xs = xb + (size_t)(4 * ig4) * 128 + 4 * dq;
    #pragma unroll
    for (int r = 0; r < 4; ++r) xv[r] = *(const float4*)(xs + r * 128);
    stage_x(0, xv);
    stage_T(0, 0);
  }
  __syncthreads();

  for (int c = 0; c < 8; ++c) {
    const int p = c & 1;
    float4 xv[4];
    if (c < 7) {  // issue next chunk's loads; complete under MFMA below
      const float* xs = xb + (size_t)(128 * (c + 1) + 4 * ig4) * 128 + 4 * dq;
      #pragma unroll
      for (int r = 0; r < 4; ++r) xv[r] = *(const float4*)(xs + r * 128);
    }
    // MFMA on current buffer: 4 K-steps of 32
    #pragma unroll
    for (int s = 0; s < 4; ++s) {
      const int gk = 4 * s + kq;
      half8 af =
          *(const half8*)&u_.p3.To[p][oA * 128 + ((gk ^ swA) & 15) * 8];
      half8 b0 =
          *(const half8*)&u_.p3.Xh[p][d0 * 128 + ((gk ^ swB0) & 15) * 8];
      half8 b1 =
          *(const half8*)&u_.p3.Xh[p][d1 * 128 + ((gk ^ swB1) & 15) * 8];
      acc0 = __builtin_amdgcn_mfma_f32_16x16x32_f16(af, b0, acc0, 0, 0, 0);
      acc1 = __builtin_amdgcn_mfma_f32_16x16x32_f16(af, b1, acc1, 0, 0, 0);
    }
    if (c < 7) {
      stage_x(p ^ 1, xv);
      stage_T(c + 1, p ^ 1);
    }
    __syncthreads();
  }

  // ---- store: C tile row = o (4*kq+rg), col = d (ml) ----
  #pragma unroll
  for (int rg = 0; rg < 4; ++rg) {
    const int o = 16 * ota + 4 * kq + rg;
    float* op = out + ((size_t)nb * 64 + o) * 512 + m * 128;
    op[d0] = acc0[rg];
    op[d1] = acc1[rg];
  }
}

extern "C" void kernel_launch(void* const* d_in, const int* in_sizes, int n_in,
                              void* d_out, int out_size, void* d_ws, size_t ws_size,
                              hipStream_t stream) {
  const float* x = (const float*)d_in[0];  // [64][1024][128] fp32
  const float* w = (const float*)d_in[1];  // [4][64][128] fp32
  float* out = (float*)d_out;              // [64][64][512] fp32
  ot_fused_kernel<<<256, 1024, 0, stream>>>(x, w, out);
}